// Round 9
// baseline (196.690 us; speedup 1.0000x reference)
//
#include <hip/hip_runtime.h>

// Problem constants (match reference)
#define B 32
#define S 32
#define N 128
#define U 64
#define E 2
#define NCLS 5

// R16: split-K=4 at the occupancy ceiling. R15 (split-K=2, 16 waves/CU,
// constant per-CU bytes) gave the first real win (209->196): the step is
// latency-slop-bound and shrinks with waves/SIMD at constant traffic.
// Extrapolate: 256-thr blocks = 4 waves sharing ONE row-pair; wave k owns
// m-quarter (aggregate) and u-quarter (msg/gates/rh); partials meet in LDS.
// Grid B*64=2048 = 8 blocks/CU = 32 waves/CU = 8 waves/SIMD (ceiling).
// Per-CU weight traffic unchanged (32 waves x 32KB = 1MB/step). Requires
// VGPR<=64: launch_bounds(256,8), small unrolls (4 on the 5-stream gate
// loop), SGPR-provable A addresses, 2-row state. If the allocator can't hit
// 64, occupancy falls back to 4/SIMD and we expect ~R15 parity (null).

__device__ __forceinline__ float sigmoid_f(float x) {
    return __fdividef(1.f, 1.f + __expf(-x));
}
__device__ __forceinline__ float tanh_f(float x) {
    float t = __expf(-2.f * fabsf(x));
    float y = __fdividef(1.f - t, 1.f + t);
    return copysignf(y, x);
}
// broadcast lane u's value of v to all lanes (VALU pipe, no LDS)
__device__ __forceinline__ float bcast(float v, int u) {
    return __uint_as_float(__builtin_amdgcn_readlane(__float_as_uint(v), u));
}

template <int FIRST, int LAST>
__global__ __launch_bounds__(256, 8) void k_step(
    const float* __restrict__ x, const int* __restrict__ lens,
    const float* __restrict__ hin, float* __restrict__ hout,
    const float* __restrict__ A, const float* __restrict__ Wmsg,
    const float* __restrict__ bmsg, const float* __restrict__ Wg,
    const float* __restrict__ Ug, const float* __restrict__ bg,
    const float* __restrict__ fcw, float* __restrict__ partial, int l) {
    // partial-reduce buffers: [khalf][...][lane]   (14 KB total)
    __shared__ float sred[4][2][2][64];   // [k][row][edge][lane]  4 KB
    __shared__ float avred[4][2][64];     // [k][row][lane]        2 KB
    __shared__ float gred[4][3][2][64];   // [k][zrc][row][lane]   6 KB
    __shared__ float c2red[4][2][64];     // [k][row][lane]        2 KB
    int tid = threadIdx.x;
    int k = tid >> 6, lane = tid & 63;
    int b = blockIdx.x >> 6;
    int j = blockIdx.x & 63;             // row-pair index within batch
    int n0 = __builtin_amdgcn_readfirstlane(j * 2);
    int u0 = __builtin_amdgcn_readfirstlane(k * 16);   // this wave's u-range
    int m0 = __builtin_amdgcn_readfirstlane(k * 32);   // this wave's m-range

    const float* __restrict__ hsrc;
    if (FIRST) {
        int idx = lens[b] - 1;
        idx = idx < 0 ? 0 : (idx > S - 1 ? S - 1 : idx);
        hsrc = x + (size_t)(b * S + idx) * N * U;
    } else {
        hsrc = hin + (size_t)b * N * U;
    }

    float hv0 = hsrc[(n0 + 0) * U + lane];
    float hv1 = hsrc[(n0 + 1) * U + lane];

    // ---- aggregate partials over this wave's m-quarter (32 m's)
    float s00 = 0.f, s01 = 0.f, s10 = 0.f, s11 = 0.f;  // [row][edge]
    {
        const float4* A00 = (const float4*)(A + (((size_t)b * E + 0) * N + n0 + 0) * N + m0);
        const float4* A10 = (const float4*)(A + (((size_t)b * E + 0) * N + n0 + 1) * N + m0);
        const float4* A01 = (const float4*)(A + (((size_t)b * E + 1) * N + n0 + 0) * N + m0);
        const float4* A11 = (const float4*)(A + (((size_t)b * E + 1) * N + n0 + 1) * N + m0);
#pragma unroll 4
        for (int m4 = 0; m4 < 8; ++m4) {
            float4 a00 = A00[m4], a10 = A10[m4], a01 = A01[m4], a11 = A11[m4];
            float q0 = hsrc[(m0 + m4 * 4 + 0) * U + lane];
            float q1 = hsrc[(m0 + m4 * 4 + 1) * U + lane];
            float q2 = hsrc[(m0 + m4 * 4 + 2) * U + lane];
            float q3 = hsrc[(m0 + m4 * 4 + 3) * U + lane];
            s00 = fmaf(a00.x, q0, s00); s00 = fmaf(a00.y, q1, s00);
            s00 = fmaf(a00.z, q2, s00); s00 = fmaf(a00.w, q3, s00);
            s10 = fmaf(a10.x, q0, s10); s10 = fmaf(a10.y, q1, s10);
            s10 = fmaf(a10.z, q2, s10); s10 = fmaf(a10.w, q3, s10);
            s01 = fmaf(a01.x, q0, s01); s01 = fmaf(a01.y, q1, s01);
            s01 = fmaf(a01.z, q2, s01); s01 = fmaf(a01.w, q3, s01);
            s11 = fmaf(a11.x, q0, s11); s11 = fmaf(a11.y, q1, s11);
            s11 = fmaf(a11.z, q2, s11); s11 = fmaf(a11.w, q3, s11);
        }
    }
    sred[k][0][0][lane] = s00;
    sred[k][0][1][lane] = s01;
    sred[k][1][0][lane] = s10;
    sred[k][1][1][lane] = s11;
    __syncthreads();
    s00 = (sred[0][0][0][lane] + sred[1][0][0][lane]) + (sred[2][0][0][lane] + sred[3][0][0][lane]);
    s01 = (sred[0][0][1][lane] + sred[1][0][1][lane]) + (sred[2][0][1][lane] + sred[3][0][1][lane]);
    s10 = (sred[0][1][0][lane] + sred[1][1][0][lane]) + (sred[2][1][0][lane] + sred[3][1][0][lane]);
    s11 = (sred[0][1][1][lane] + sred[1][1][1][lane]) + (sred[2][1][1][lane] + sred[3][1][1][lane]);

    // ---- msg partials over this wave's u-quarter (bias carried by k==0)
    float av0, av1;
    {
        float bm = (k == 0) ? bmsg[l * U + lane] : 0.f;
        av0 = bm; av1 = bm;
        const float* W0 = Wmsg + (size_t)(l * E + 0) * U * U + lane;
        const float* W1 = W0 + U * U;
#pragma unroll 8
        for (int uu = 0; uu < 16; ++uu) {
            int u = u0 + uu;
            float w = W0[u * U];
            av0 = fmaf(bcast(s00, u), w, av0);
            av1 = fmaf(bcast(s10, u), w, av1);
        }
#pragma unroll 8
        for (int uu = 0; uu < 16; ++uu) {
            int u = u0 + uu;
            float w = W1[u * U];
            av0 = fmaf(bcast(s01, u), w, av0);
            av1 = fmaf(bcast(s11, u), w, av1);
        }
    }
    avred[k][0][lane] = av0;
    avred[k][1][lane] = av1;
    __syncthreads();
    av0 = (avred[0][0][lane] + avred[1][0][lane]) + (avred[2][0][lane] + avred[3][0][lane]);
    av1 = (avred[0][1][lane] + avred[1][1][lane]) + (avred[2][1][lane] + avred[3][1][lane]);

    // ---- gate matmul partials over this wave's u-quarter
    const float* Wg0 = Wg + (size_t)l * 3 * U * U + lane;
    const float* Wg1 = Wg0 + U * U;
    const float* Wg2 = Wg1 + U * U;
    const float* Ug0 = Ug + (size_t)l * 3 * U * U + lane;
    const float* Ug1 = Ug0 + U * U;
    const float* Ug2 = Ug1 + U * U;
    float accz0, accz1, accr0, accr1, accc0, accc1;
    {
        float bz = (k == 0) ? bg[(l * 3 + 0) * U + lane] : 0.f;
        float br = (k == 0) ? bg[(l * 3 + 1) * U + lane] : 0.f;
        float bcc = (k == 0) ? bg[(l * 3 + 2) * U + lane] : 0.f;
        accz0 = bz; accz1 = bz;
        accr0 = br; accr1 = br;
        accc0 = bcc; accc1 = bcc;
#pragma unroll 4
        for (int uu = 0; uu < 16; ++uu) {
            int u = u0 + uu;
            float w0 = Wg0[u * U], w1 = Wg1[u * U], w2 = Wg2[u * U];
            float g0 = Ug0[u * U], g1 = Ug1[u * U];
            float a0 = bcast(av0, u), a1 = bcast(av1, u);
            float h0 = bcast(hv0, u), h1 = bcast(hv1, u);
            accz0 = fmaf(a0, w0, accz0); accz0 = fmaf(h0, g0, accz0);
            accz1 = fmaf(a1, w0, accz1); accz1 = fmaf(h1, g0, accz1);
            accr0 = fmaf(a0, w1, accr0); accr0 = fmaf(h0, g1, accr0);
            accr1 = fmaf(a1, w1, accr1); accr1 = fmaf(h1, g1, accr1);
            accc0 = fmaf(a0, w2, accc0);
            accc1 = fmaf(a1, w2, accc1);
        }
    }
    gred[k][0][0][lane] = accz0; gred[k][0][1][lane] = accz1;
    gred[k][1][0][lane] = accr0; gred[k][1][1][lane] = accr1;
    gred[k][2][0][lane] = accc0; gred[k][2][1][lane] = accc1;
    __syncthreads();
    accz0 = (gred[0][0][0][lane] + gred[1][0][0][lane]) + (gred[2][0][0][lane] + gred[3][0][0][lane]);
    accz1 = (gred[0][0][1][lane] + gred[1][0][1][lane]) + (gred[2][0][1][lane] + gred[3][0][1][lane]);
    accr0 = (gred[0][1][0][lane] + gred[1][1][0][lane]) + (gred[2][1][0][lane] + gred[3][1][0][lane]);
    accr1 = (gred[0][1][1][lane] + gred[1][1][1][lane]) + (gred[2][1][1][lane] + gred[3][1][1][lane]);
    accc0 = (gred[0][2][0][lane] + gred[1][2][0][lane]) + (gred[2][2][0][lane] + gred[3][2][0][lane]);
    accc1 = (gred[0][2][1][lane] + gred[1][2][1][lane]) + (gred[2][2][1][lane] + gred[3][2][1][lane]);

    // ---- rh matmul partials over this wave's u-quarter
    float rh0 = sigmoid_f(accr0) * hv0;
    float rh1 = sigmoid_f(accr1) * hv1;
    float c20 = 0.f, c21 = 0.f;
#pragma unroll 8
    for (int uu = 0; uu < 16; ++uu) {
        int u = u0 + uu;
        float g2 = Ug2[u * U];
        c20 = fmaf(bcast(rh0, u), g2, c20);
        c21 = fmaf(bcast(rh1, u), g2, c21);
    }
    c2red[k][0][lane] = c20;
    c2red[k][1][lane] = c21;
    __syncthreads();
    accc0 += (c2red[0][0][lane] + c2red[1][0][lane]) + (c2red[2][0][lane] + c2red[3][0][lane]);
    accc1 += (c2red[0][1][lane] + c2red[1][1][lane]) + (c2red[2][1][lane] + c2red[3][1][lane]);

    float zg0 = sigmoid_f(accz0), zg1 = sigmoid_f(accz1);
    float hn0 = (1.f - zg0) * hv0 + zg0 * tanh_f(accc0);
    float hn1 = (1.f - zg1) * hv1 + zg1 * tanh_f(accc1);

    if (!LAST) {
        if (k == 0) {
            hout[((size_t)b * N + n0 + 0) * U + lane] = hn0;
            hout[((size_t)b * N + n0 + 1) * U + lane] = hn1;
        }
    } else {
        // classification partial over this block's 2 rows (k==0 wave only)
        if (k == 0) {
            float lg0[NCLS], lg1[NCLS];
            float rv0 = hn0 > 0.f ? hn0 : 0.f;
            float rv1 = hn1 > 0.f ? hn1 : 0.f;
#pragma unroll
            for (int c = 0; c < NCLS; c++) {
                float w = fcw[lane * NCLS + c];
                lg0[c] = rv0 * w;
                lg1[c] = rv1 * w;
            }
#pragma unroll
            for (int off = 32; off; off >>= 1) {
#pragma unroll
                for (int c = 0; c < NCLS; c++) {
                    lg0[c] += __shfl_xor(lg0[c], off, 64);
                    lg1[c] += __shfl_xor(lg1[c], off, 64);
                }
            }
            if (lane == 0) {
#pragma unroll
                for (int c = 0; c < NCLS; c++)
                    partial[(size_t)(b * 64 + j) * NCLS + c] = fmaxf(lg0[c], lg1[c]);
            }
        }
    }
}

// ---------------------------------------------------------------------------
// k_final: out[b][c] = max over 64 row-pair partials + fc_b
__global__ void k_final(const float* __restrict__ partial, const float* __restrict__ fcb,
                        float* __restrict__ out) {
    int b = blockIdx.x, c = threadIdx.x;
    if (c < NCLS) {
        float m = -3.4e38f;
        for (int jj = 0; jj < 64; ++jj)
            m = fmaxf(m, partial[(size_t)(b * 64 + jj) * NCLS + c]);
        out[b * NCLS + c] = m + fcb[c];
    }
}

// ---------------------------------------------------------------------------
extern "C" void kernel_launch(void* const* d_in, const int* in_sizes, int n_in,
                              void* d_out, int out_size, void* d_ws, size_t ws_size,
                              hipStream_t stream) {
    const float* x    = (const float*)d_in[0];
    const int*   lens = (const int*)d_in[1];
    const float* A    = (const float*)d_in[2];
    const float* Wmsg = (const float*)d_in[3];
    const float* bmsg = (const float*)d_in[4];
    const float* Wg   = (const float*)d_in[5];
    const float* Ug   = (const float*)d_in[6];
    const float* bg   = (const float*)d_in[7];
    const float* fcw  = (const float*)d_in[8];
    const float* fcb  = (const float*)d_in[9];
    float* out = (float*)d_out;

    float* hA      = (float*)d_ws;                   // [B][N][U]
    float* hB      = hA + (size_t)B * N * U;         // [B][N][U]
    float* partial = hB + (size_t)B * N * U;         // [B][64][NCLS]

    // steps 0-2: layer 0; steps 3-5: layer 1
    k_step<1, 0><<<B * 64, 256, 0, stream>>>(x, lens, nullptr, hA, A, Wmsg, bmsg, Wg, Ug, bg, fcw, partial, 0);
    k_step<0, 0><<<B * 64, 256, 0, stream>>>(x, lens, hA, hB, A, Wmsg, bmsg, Wg, Ug, bg, fcw, partial, 0);
    k_step<0, 0><<<B * 64, 256, 0, stream>>>(x, lens, hB, hA, A, Wmsg, bmsg, Wg, Ug, bg, fcw, partial, 0);
    k_step<0, 0><<<B * 64, 256, 0, stream>>>(x, lens, hA, hB, A, Wmsg, bmsg, Wg, Ug, bg, fcw, partial, 1);
    k_step<0, 0><<<B * 64, 256, 0, stream>>>(x, lens, hB, hA, A, Wmsg, bmsg, Wg, Ug, bg, fcw, partial, 1);
    k_step<0, 1><<<B * 64, 256, 0, stream>>>(x, lens, hA, hB, A, Wmsg, bmsg, Wg, Ug, bg, fcw, partial, 1);
    k_final<<<B, 64, 0, stream>>>(partial, fcb, out);
}